// Round 1
// baseline (182.033 us; speedup 1.0000x reference)
//
#include <hip/hip_runtime.h>
#include <math.h>

#define WAVE 64
#define BDIM 1024
#define VPT4 13            // ceil(ceil(50257/4)/1024) -> supports V <= 53248

// ---------------- Kernel A: p_copy[n] = sigmoid(dot(hidden[n], W) + b) -------
__global__ void pcopy_kernel(const float* __restrict__ hidden,
                             const float* __restrict__ W,
                             const float* __restrict__ b,
                             float* __restrict__ p_copy,
                             int N, int D) {
    int gtid = blockIdx.x * blockDim.x + threadIdx.x;
    int row  = gtid / WAVE;
    int lane = gtid & (WAVE - 1);
    if (row >= N) return;
    const float* h = hidden + (size_t)row * D;
    float acc = 0.f;
    for (int e = lane * 4; e + 3 < D; e += WAVE * 4) {
        float4 hv = *(const float4*)(h + e);
        float4 wv = *(const float4*)(W + e);
        acc += hv.x * wv.x + hv.y * wv.y + hv.z * wv.z + hv.w * wv.w;
    }
    #pragma unroll
    for (int off = 32; off >= 1; off >>= 1)
        acc += __shfl_xor(acc, off, WAVE);
    if (lane == 0) {
        float z = acc + b[0];
        p_copy[row] = 1.f / (1.f + __expf(-z));
    }
}

// ------- Kernel B: out[n,:] = softmax(x[n,:]) * (1 - p_copy[n]), row in regs -
__global__ __launch_bounds__(BDIM, 4) void softmax_kernel(
        const float* __restrict__ x,
        const float* __restrict__ p_copy,
        float* __restrict__ out,
        int V) {
    const int row = blockIdx.x;
    const int tid = threadIdx.x;
    const float* xr = x + (size_t)row * V;
    float* outr = out + (size_t)row * V;

    float v[VPT4 * 4];
    // ---- load (coalesced float4, tail scalar) ----
    #pragma unroll
    for (int i = 0; i < VPT4; ++i) {
        int e = (i * BDIM + tid) * 4;
        if (e + 3 < V) {
            float4 t = *(const float4*)(xr + e);
            v[4*i+0] = t.x; v[4*i+1] = t.y; v[4*i+2] = t.z; v[4*i+3] = t.w;
        } else {
            #pragma unroll
            for (int k = 0; k < 4; ++k)
                v[4*i+k] = (e + k < V) ? xr[e + k] : -INFINITY;
        }
    }

    // ---- block max ----
    __shared__ float red_max[BDIM / WAVE];
    __shared__ float red_sum[BDIM / WAVE];
    const int wid  = tid / WAVE;
    const int lane = tid % WAVE;

    float m = -INFINITY;
    #pragma unroll
    for (int j = 0; j < VPT4 * 4; ++j) m = fmaxf(m, v[j]);
    #pragma unroll
    for (int off = 32; off >= 1; off >>= 1)
        m = fmaxf(m, __shfl_xor(m, off, WAVE));
    if (lane == 0) red_max[wid] = m;
    __syncthreads();
    if (wid == 0) {
        float t = (lane < BDIM / WAVE) ? red_max[lane] : -INFINITY;
        #pragma unroll
        for (int off = 8; off >= 1; off >>= 1)
            t = fmaxf(t, __shfl_xor(t, off, WAVE));
        if (lane == 0) red_max[0] = t;
    }
    __syncthreads();
    m = red_max[0];

    // ---- exp + block sum ----
    float s = 0.f;
    #pragma unroll
    for (int j = 0; j < VPT4 * 4; ++j) {
        v[j] = __expf(v[j] - m);   // exp(-inf)=0 for padding lanes
        s += v[j];
    }
    #pragma unroll
    for (int off = 32; off >= 1; off >>= 1)
        s += __shfl_xor(s, off, WAVE);
    if (lane == 0) red_sum[wid] = s;
    __syncthreads();
    if (wid == 0) {
        float t = (lane < BDIM / WAVE) ? red_sum[lane] : 0.f;
        #pragma unroll
        for (int off = 8; off >= 1; off >>= 1)
            t += __shfl_xor(t, off, WAVE);
        if (lane == 0) red_sum[0] = t;
    }
    __syncthreads();
    s = red_sum[0];

    // ---- scale + store ----
    const float scale = (1.f - p_copy[row]) / s;
    #pragma unroll
    for (int i = 0; i < VPT4; ++i) {
        int e = (i * BDIM + tid) * 4;
        if (e + 3 < V) {
            float4 t;
            t.x = v[4*i+0] * scale; t.y = v[4*i+1] * scale;
            t.z = v[4*i+2] * scale; t.w = v[4*i+3] * scale;
            *(float4*)(outr + e) = t;
        } else {
            #pragma unroll
            for (int k = 0; k < 4; ++k)
                if (e + k < V) outr[e + k] = v[4*i+k] * scale;
        }
    }
}

// ------- Kernel C: copy_prob[n,:] = scatter-add over s of attn[n,s]*p_copy[n]
__global__ void scatter_kernel(const float* __restrict__ attn,
                               const float* __restrict__ p_copy,
                               const int* __restrict__ src_map,
                               float* __restrict__ copy_out,
                               int S, int C, int T) {
    const int n = blockIdx.x;
    const int b = n / T;
    extern __shared__ float bins[];
    for (int j = threadIdx.x; j < C; j += blockDim.x) bins[j] = 0.f;
    __syncthreads();
    const float pc = p_copy[n];
    const float* ar = attn + (size_t)n * S;
    const int* sm = src_map + (size_t)b * S;
    for (int s = threadIdx.x; s < S; s += blockDim.x)
        atomicAdd(&bins[sm[s]], ar[s] * pc);
    __syncthreads();
    float* outr = copy_out + (size_t)n * C;
    for (int j = threadIdx.x; j < C; j += blockDim.x)
        outr[j] = bins[j];
}

extern "C" void kernel_launch(void* const* d_in, const int* in_sizes, int n_in,
                              void* d_out, int out_size, void* d_ws, size_t ws_size,
                              hipStream_t stream) {
    const float* hidden  = (const float*)d_in[0];
    const float* orig    = (const float*)d_in[1];
    const float* attn    = (const float*)d_in[2];
    const int*   src_map = (const int*)  d_in[3];
    const float* W       = (const float*)d_in[4];
    const float* b       = (const float*)d_in[5];

    const int D = in_sizes[4];               // 1024
    const int N = in_sizes[0] / D;           // 2048
    const int V = in_sizes[1] / N;           // 50257
    const int S = in_sizes[2] / N;           // 400
    const int B = in_sizes[3] / S;           // 32
    const int T = N / B;                     // 64
    const int C = out_size / N - V;          // 600

    float* out_prob = (float*)d_out;
    float* copy_out = (float*)d_out + (size_t)N * V;
    float* p_copy   = (float*)d_ws;          // N floats of scratch

    // A: one wave per row
    {
        int threads = 256;
        int blocks  = (N * WAVE + threads - 1) / threads;
        pcopy_kernel<<<blocks, threads, 0, stream>>>(hidden, W, b, p_copy, N, D);
    }
    // B: one block per row, row register-resident
    softmax_kernel<<<N, BDIM, 0, stream>>>(orig, p_copy, out_prob, V);
    // C: one block per row, LDS histogram
    scatter_kernel<<<N, 256, C * sizeof(float), stream>>>(attn, p_copy, src_map,
                                                          copy_out, S, C, T);
}